// Round 10
// baseline (93.373 us; speedup 1.0000x reference)
//
#include <hip/hip_runtime.h>

#define BATCH   16384
#define NKNOW   128
#define NEDGE   253
#define RPB     16

typedef __attribute__((ext_vector_type(8))) short  s16x8;   // 8 bf16 MFMA operand
typedef __attribute__((ext_vector_type(4))) float  f32x4;   // MFMA accumulator
typedef __attribute__((ext_vector_type(4))) int    i32x4;

typedef unsigned short u16;
typedef unsigned int   u32;
typedef unsigned long long u64;

__device__ __forceinline__ float sigm(float x) { return 1.0f / (1.0f + __expf(-x)); }

__device__ __forceinline__ u16 f2bf_rn(float x) {
    u32 u = __float_as_uint(x);
    u += 0x7FFFu + ((u >> 16) & 1u);
    return (u16)(u >> 16);
}
__device__ __forceinline__ float bf2f(u16 h) { return __uint_as_float(((u32)h) << 16); }

// ======================= K1: prep3 (wave-per-row gather + lane0 chain) =====
// 4096 blocks x 256 thr; wave w owns row = blockIdx*4 + w.
// Phase 1 (per wave, max MLP): gather condi row, sigmoid+sqrt -> sP[w][slot];
//   know/diff -> dhi/dlo global (coalesced); ballot -> know mask.
// Phase 2: lane 0 of each wave runs the 126-step chain from its own sP,
//   masking+packing bf16 pairs into sM/sL (LDS).
// Phase 3: wave copies sM/sL -> mhi32/mlo32 coalesced.
__global__ __launch_bounds__(256, 4) void prep3(
    const int*   __restrict__ user_ids,
    const int*   __restrict__ item_ids,
    const float* __restrict__ item_know,
    const float* __restrict__ priori,
    const float* __restrict__ condi_p,
    const float* __restrict__ condi_n,
    const float* __restrict__ item_diff_w,
    const float* __restrict__ Wu,
    const float* __restrict__ Wi,
    u16*         __restrict__ wsp,
    u32*         __restrict__ mhi32,    // [BATCH][64] u32 = masked bf16 pairs
    u32*         __restrict__ mlo32,
    u16*         __restrict__ dhi,      // [BATCH][128] bf16
    u16*         __restrict__ dlo)
{
    __shared__ float4 sP[4][127];       // [wave][slot 1..126]; ~8.1 KB
    __shared__ u32    sM[4][64];        // mastery hi pairs
    __shared__ u32    sL[4][64];        // mastery lo pairs

    const int tid = threadIdx.x;
    const int wid = tid >> 6, j = tid & 63;
    const int row = blockIdx.x * 4 + wid;
    const int uid = user_ids[row], iid = item_ids[row];
    const float* cp = condi_p + (size_t)uid * NEDGE;
    const float* cn = condi_n + (size_t)uid * NEDGE;
    const float* kw = item_know   + (size_t)row * NKNOW;
    const float* dw = item_diff_w + (size_t)iid * NKNOW;

    // ---- Phase 1: all independent loads issued up front (R7-proven) ------
    float a0p = cp[127 + j], a0n = cn[127 + j], b0p = cp[1 + j], b0n = cn[1 + j];
    float a1p = 0.f, a1n = 0.f, b1p = 0.f, b1n = 0.f;
    if (j < 62) { a1p = cp[191 + j]; a1n = cn[191 + j]; b1p = cp[65 + j]; b1n = cn[65 + j]; }
    float k0 = kw[j], k1 = kw[64 + j];
    float d0 = dw[j], d1 = dw[64 + j];
    float c0p = cp[0], c0n = cn[0], pri = priori[(size_t)uid * NKNOW];

    float4 sA;
    sA.x = sqrtf(sigm(a0p)); sA.y = sqrtf(sigm(a0n));
    sA.z = sqrtf(sigm(b0p)); sA.w = sqrtf(sigm(b0n));
    sP[wid][1 + j] = sA;
    if (j < 62) {
        float4 sB;
        sB.x = sqrtf(sigm(a1p)); sB.y = sqrtf(sigm(a1n));
        sB.z = sqrtf(sigm(b1p)); sB.w = sqrtf(sigm(b1n));
        sP[wid][65 + j] = sB;
    }

    float dv0 = sigm(d0) * k0, dv1 = sigm(d1) * k1;       // know in {0,1} -> exact
    u16 h0 = f2bf_rn(dv0), h1 = f2bf_rn(dv1);
    dhi[(size_t)row * NKNOW + j]      = h0;
    dhi[(size_t)row * NKNOW + 64 + j] = h1;
    dlo[(size_t)row * NKNOW + j]      = f2bf_rn(dv0 - bf2f(h0));
    dlo[(size_t)row * NKNOW + 64 + j] = f2bf_rn(dv1 - bf2f(h1));

    const u64 b0m = __ballot(k0 > 0.5f);
    const u64 b1m = __ballot(k1 > 0.5f);

    // merged conv_w: blocks 0..255 convert Wu/Wi fp32 -> bf16 hi/lo in wsp
    if (blockIdx.x < 256) {
        int i = blockIdx.x * 256 + tid;                   // 0..65535
        bool isU = i < 32768;
        int  jj  = isU ? i : i - 32768;
        float w  = isU ? Wu[jj] : Wi[jj];
        u16 h = f2bf_rn(w);
        u16 l = f2bf_rn(w - bf2f(h));
        int base = isU ? 0 : 65536;
        wsp[base + jj]         = h;
        wsp[base + 32768 + jj] = l;
    }
    __syncthreads();

    // ---- Phase 2: serial chain on lane 0 of each wave (R5-proven math) ---
    if (j == 0) {
        const int w = wid;
        float p0 = sigm(pri);
        float p1 = fmaf(p0, sigm(c0p) - sigm(c0n), sigm(c0n));
        {
            float v0 = (b0m & 1ull) ? p0 : 0.f;
            float v1 = (b0m & 2ull) ? p1 : 0.f;
            u16 q0 = f2bf_rn(v0), q1 = f2bf_rn(v1);
            sM[w][0] = (u32)q0 | ((u32)q1 << 16);
            sL[w][0] = (u32)f2bf_rn(v0 - bf2f(q0)) | ((u32)f2bf_rn(v1 - bf2f(q1)) << 16);
        }

        float pm2 = p0, pm1 = p1, pendm = 0.f;
        float4 A[7], Bv[7];

#define LOADB(buf, bi_)                                               \
    _Pragma("unroll")                                                 \
    for (int t = 0; t < 7; ++t) buf[t] = sP[w][1 + 7 * (bi_) + t];

#define STEPS(buf, bi_)                                               \
    _Pragma("unroll")                                                 \
    for (int t = 0; t < 7; ++t) {                                     \
        const int k = 2 + 7 * (bi_) + t;                              \
        float4 s = buf[t];                                            \
        float ta = fmaf(pm2, s.x - s.y, s.y);                         \
        float tb = fmaf(pm1, s.z - s.w, s.w);                         \
        float pk = ta * tb;                                           \
        bool bit = (k < 64) ? ((b0m >> k) & 1ull) : ((b1m >> (k - 64)) & 1ull); \
        float pkm = bit ? pk : 0.f;                                   \
        if (k & 1) {                                                  \
            u16 q0 = f2bf_rn(pendm), q1 = f2bf_rn(pkm);               \
            sM[w][k >> 1] = (u32)q0 | ((u32)q1 << 16);                \
            sL[w][k >> 1] = (u32)f2bf_rn(pendm - bf2f(q0)) |          \
                            ((u32)f2bf_rn(pkm - bf2f(q1)) << 16);     \
        } else pendm = pkm;                                           \
        pm2 = pm1; pm1 = pk;                                          \
    }
        LOADB(A, 0);
        LOADB(Bv, 1);  STEPS(A, 0);
        LOADB(A, 2);   STEPS(Bv, 1);
        LOADB(Bv, 3);  STEPS(A, 2);
        LOADB(A, 4);   STEPS(Bv, 3);
        LOADB(Bv, 5);  STEPS(A, 4);
        LOADB(A, 6);   STEPS(Bv, 5);
        LOADB(Bv, 7);  STEPS(A, 6);
        LOADB(A, 8);   STEPS(Bv, 7);
        LOADB(Bv, 9);  STEPS(A, 8);
        LOADB(A, 10);  STEPS(Bv, 9);
        LOADB(Bv, 11); STEPS(A, 10);
        LOADB(A, 12);  STEPS(Bv, 11);
        LOADB(Bv, 13); STEPS(A, 12);
        LOADB(A, 14);  STEPS(Bv, 13);
        LOADB(Bv, 15); STEPS(A, 14);
        LOADB(A, 16);  STEPS(Bv, 15);
        LOADB(Bv, 17); STEPS(A, 16);
        STEPS(Bv, 17);
#undef LOADB
#undef STEPS
    }
    __syncthreads();

    // ---- Phase 3: coalesced copy-out (wave w -> row's 64 u32 pairs) ------
    mhi32[(size_t)row * 64 + j] = sM[wid][j];
    mlo32[(size_t)row * 64 + j] = sL[wid][j];
}

// ======================= K2: gemm (R8-proven, verbatim) ====================
__global__ __launch_bounds__(256, 2) void gemm_ncd(
    const int*   __restrict__ item_ids,
    const float* __restrict__ item_disc_w,
    const float* __restrict__ bu,
    const float* __restrict__ bi,
    const u16*   __restrict__ wsp,
    const u32*   __restrict__ mhi32,
    const u32*   __restrict__ mlo32,
    const u32*   __restrict__ dhi32,
    const u32*   __restrict__ dlo32,
    float*       __restrict__ out)
{
    __shared__ float sRed[4][32];

    const int tid  = threadIdx.x;
    const int lane = tid & 63;
    const int wid  = tid >> 6;
    const int l15  = lane & 15, lq = lane >> 4;
    const int r0   = blockIdx.x * 32;

    const u16* WuH = wsp;
    const u16* WuL = wsp + 32768;
    const u16* WiH = wsp + 65536;
    const u16* WiL = wsp + 98304;

    float rowsum[2][4] = {{0.f,0.f,0.f,0.f},{0.f,0.f,0.f,0.f}};

    #pragma unroll 1
    for (int t = 0; t < 4; ++t) {
        const int hcol = wid * 64 + t * 16 + l15;
        s16x8 uh[4], ul[4], ih[4], il[4];
        #pragma unroll
        for (int kc = 0; kc < 4; ++kc) {
            const int ke = kc * 32 + lq * 8;
            uh[kc] = *(const s16x8*)(WuH + hcol * NKNOW + ke);
            ul[kc] = *(const s16x8*)(WuL + hcol * NKNOW + ke);
            ih[kc] = *(const s16x8*)(WiH + hcol * NKNOW + ke);
            il[kc] = *(const s16x8*)(WiL + hcol * NKNOW + ke);
        }
        const float bub = bu[hcol], bib = bi[hcol];

        #pragma unroll
        for (int rg = 0; rg < 2; ++rg) {
            const int row = r0 + rg * 16 + l15;
            f32x4 accU = {0.f, 0.f, 0.f, 0.f};
            f32x4 accV = {0.f, 0.f, 0.f, 0.f};
            #pragma unroll
            for (int kc = 0; kc < 4; ++kc) {
                const int aoff = row * 64 + kc * 16 + lq * 4;
                s16x8 mh = *(const s16x8*)(mhi32 + aoff);
                s16x8 mlv = *(const s16x8*)(mlo32 + aoff);
                s16x8 dh = *(const s16x8*)(dhi32 + aoff);
                s16x8 dl = *(const s16x8*)(dlo32 + aoff);
                accU = __builtin_amdgcn_mfma_f32_16x16x32_bf16(mh, uh[kc], accU, 0, 0, 0);
                accU = __builtin_amdgcn_mfma_f32_16x16x32_bf16(mh, ul[kc], accU, 0, 0, 0);
                accU = __builtin_amdgcn_mfma_f32_16x16x32_bf16(mlv, uh[kc], accU, 0, 0, 0);
                accV = __builtin_amdgcn_mfma_f32_16x16x32_bf16(dh, ih[kc], accV, 0, 0, 0);
                accV = __builtin_amdgcn_mfma_f32_16x16x32_bf16(dh, il[kc], accV, 0, 0, 0);
                accV = __builtin_amdgcn_mfma_f32_16x16x32_bf16(dl, ih[kc], accV, 0, 0, 0);
            }
            #pragma unroll
            for (int j = 0; j < 4; ++j) {
                float x = accU[j] + bub;
                float u = 1.0f - 2.0f / (1.0f + __expf(2.0f * x));   // tanh
                float v = sigm(accV[j] + bib);
                rowsum[rg][j] += u * v;
            }
        }
    }

    #pragma unroll
    for (int rg = 0; rg < 2; ++rg)
        #pragma unroll
        for (int j = 0; j < 4; ++j) {
            float v = rowsum[rg][j];
            v += __shfl_xor(v, 1);
            v += __shfl_xor(v, 2);
            v += __shfl_xor(v, 4);
            v += __shfl_xor(v, 8);
            if (l15 == 0) sRed[wid][rg * 16 + lq * 4 + j] = v;
        }
    __syncthreads();

    if (tid < 32) {
        const int row = r0 + tid;
        float s = sRed[0][tid] + sRed[1][tid] + sRed[2][tid] + sRed[3][tid];
        float disc = sigm(item_disc_w[item_ids[row]]);
        out[row] = sigm(s - disc);
    }
}

// ======================= Fallback: R1 fused kernel (proven) ================
__device__ __forceinline__ int swz(int row, int kbyte) {
    return row * 256 + (kbyte ^ ((row & 7) << 4));
}
__device__ __forceinline__ void store_pair(char* Mh, char* Ml, int r, int k0, float va, float vb) {
    int off = swz(r, k0 * 2);
    u16 ha = f2bf_rn(va); u16 la = f2bf_rn(va - bf2f(ha));
    u16 hb = f2bf_rn(vb); u16 lb = f2bf_rn(vb - bf2f(hb));
    *(u32*)(Mh + off) = (u32)ha | ((u32)hb << 16);
    *(u32*)(Ml + off) = (u32)la | ((u32)lb << 16);
}

__global__ void conv_w(const float* __restrict__ Wu, const float* __restrict__ Wi,
                       u16* __restrict__ wsp) {
    int i = blockIdx.x * 256 + threadIdx.x;
    bool isU = i < 32768;
    int  j   = isU ? i : i - 32768;
    float w  = isU ? Wu[j] : Wi[j];
    u16 h = f2bf_rn(w);
    u16 l = f2bf_rn(w - bf2f(h));
    int base = isU ? 0 : 65536;
    wsp[base + j]         = h;
    wsp[base + 32768 + j] = l;
}

__global__ __launch_bounds__(256, 3) void fused_ncd(
    const int*   __restrict__ user_ids,
    const int*   __restrict__ item_ids,
    const float* __restrict__ item_know,
    const float* __restrict__ priori,
    const float* __restrict__ condi_p,
    const float* __restrict__ condi_n,
    const float* __restrict__ item_diff_w,
    const float* __restrict__ item_disc_w,
    const float* __restrict__ bu,
    const float* __restrict__ bi,
    const u16* __restrict__ wsp,
    float*       __restrict__ out)
{
    __shared__ float sPair[RPB][508];
    __shared__ __align__(16) u16 sMhi[RPB * 128];
    __shared__ __align__(16) u16 sMlo[RPB * 128];
    __shared__ __align__(16) u16 sDhi[RPB * 128];
    __shared__ __align__(16) u16 sDlo[RPB * 128];
    __shared__ __align__(16) u16 sKmF[RPB * 128];
    __shared__ float sRed[4][RPB];
    __shared__ float sDisc[RPB];

    const int tid  = threadIdx.x;
    const int lane = tid & 63;
    const int wid  = tid >> 6;
    const int r0   = blockIdx.x * RPB;

    for (int rr = 0; rr < 4; ++rr) {
        const int r   = wid * 4 + rr;
        const int row = r0 + r;
        const int uid = user_ids[row];
        const int iid = item_ids[row];
        const float* cp = condi_p + (size_t)uid * NEDGE;
        const float* cn = condi_n + (size_t)uid * NEDGE;
        for (int e = lane; e < NEDGE; e += 64) {
            float p = sigm(cp[e]);
            float n = sigm(cn[e]);
            if (e >= 1) { p = sqrtf(p); n = sqrtf(n); }
            *(float2*)&sPair[r][2 * e] = make_float2(p, n);
        }
        const float* dw = item_diff_w + (size_t)iid * NKNOW;
        const float* kw = item_know   + (size_t)row * NKNOW;
        for (int e = lane; e < NKNOW; e += 64) {
            float kv = kw[e];
            float dv = sigm(dw[e]) * kv;
            u16 dh = f2bf_rn(dv);
            u16 dl = f2bf_rn(dv - bf2f(dh));
            int off = swz(r, 2 * e);
            *(u16*)((char*)sDhi + off) = dh;
            *(u16*)((char*)sDlo + off) = dl;
            *(u16*)((char*)sKmF + off) = (kv > 0.5f) ? (u16)0xFFFFu : (u16)0;
        }
    }
    __syncthreads();

    if (tid < RPB) {
        const int r   = tid;
        const int row = r0 + r;
        const int uid = user_ids[row];
        const int iid = item_ids[row];
        const float* P = &sPair[r][0];
        float p0 = sigm(priori[(size_t)uid * NKNOW]);
        float2 c0 = *(const float2*)&P[0];
        float p1 = c0.x * p0 + c0.y * (1.0f - p0);
        store_pair((char*)sMhi, (char*)sMlo, r, 0, p0, p1);
        float pm2 = p0, pm1 = p1, pev = 0.0f;
        for (int k = 2; k < NKNOW; ++k) {
            float2 a = *(const float2*)&P[2 * (125 + k)];
            float2 b = *(const float2*)&P[2 * (k - 1)];
            float ta = fmaf(pm2, a.x - a.y, a.y);
            float tb = fmaf(pm1, b.x - b.y, b.y);
            float pk = ta * tb;
            if (k & 1) store_pair((char*)sMhi, (char*)sMlo, r, k - 1, pev, pk);
            else       pev = pk;
            pm2 = pm1; pm1 = pk;
        }
        sDisc[r] = sigm(item_disc_w[iid]);
    }
    __syncthreads();

    const int l15 = lane & 15, lq = lane >> 4;
    const u16* WuH = wsp;
    const u16* WuL = wsp + 32768;
    const u16* WiH = wsp + 65536;
    const u16* WiL = wsp + 98304;

    float rowsum[4] = {0.f, 0.f, 0.f, 0.f};

    for (int t = 0; t < 4; ++t) {
        const int hcol = wid * 64 + t * 16 + l15;
        f32x4 accU = {0.f, 0.f, 0.f, 0.f};
        f32x4 accV = {0.f, 0.f, 0.f, 0.f};
        const u16* wuh = WuH + hcol * NKNOW;
        const u16* wul = WuL + hcol * NKNOW;
        const u16* wih = WiH + hcol * NKNOW;
        const u16* wil = WiL + hcol * NKNOW;
        #pragma unroll
        for (int kc = 0; kc < 4; ++kc) {
            const int offA = swz(l15, kc * 64 + lq * 16);
            const int ke   = kc * 32 + lq * 8;
            i32x4 km = *(const i32x4*)((const char*)sKmF + offA);
            i32x4 mh = *(const i32x4*)((const char*)sMhi + offA) & km;
            i32x4 ml = *(const i32x4*)((const char*)sMlo + offA) & km;
            s16x8 ah = *(s16x8*)&mh;
            s16x8 al = *(s16x8*)&ml;
            s16x8 bh = *(const s16x8*)((const char*)sDhi + offA);
            s16x8 bl = *(const s16x8*)((const char*)sDlo + offA);
            s16x8 uh = *(const s16x8*)(wuh + ke);
            s16x8 ul = *(const s16x8*)(wul + ke);
            s16x8 ih = *(const s16x8*)(wih + ke);
            s16x8 il = *(const s16x8*)(wil + ke);
            accU = __builtin_amdgcn_mfma_f32_16x16x32_bf16(ah, uh, accU, 0, 0, 0);
            accU = __builtin_amdgcn_mfma_f32_16x16x32_bf16(ah, ul, accU, 0, 0, 0);
            accU = __builtin_amdgcn_mfma_f32_16x16x32_bf16(al, uh, accU, 0, 0, 0);
            accV = __builtin_amdgcn_mfma_f32_16x16x32_bf16(bh, ih, accV, 0, 0, 0);
            accV = __builtin_amdgcn_mfma_f32_16x16x32_bf16(bh, il, accV, 0, 0, 0);
            accV = __builtin_amdgcn_mfma_f32_16x16x32_bf16(bl, ih, accV, 0, 0, 0);
        }
        const float bub = bu[hcol], bib = bi[hcol];
        #pragma unroll
        for (int j = 0; j < 4; ++j) {
            float x = accU[j] + bub;
            float u = 1.0f - 2.0f / (1.0f + __expf(2.0f * x));
            float v = sigm(accV[j] + bib);
            rowsum[j] += u * v;
        }
    }

    #pragma unroll
    for (int j = 0; j < 4; ++j) {
        float v = rowsum[j];
        v += __shfl_xor(v, 1);
        v += __shfl_xor(v, 2);
        v += __shfl_xor(v, 4);
        v += __shfl_xor(v, 8);
        if (l15 == 0) sRed[wid][lq * 4 + j] = v;
    }
    __syncthreads();

    if (tid < RPB) {
        float logit = sRed[0][tid] + sRed[1][tid] + sRed[2][tid] + sRed[3][tid] - sDisc[tid];
        out[r0 + tid] = sigm(logit);
    }
}

extern "C" void kernel_launch(void* const* d_in, const int* in_sizes, int n_in,
                              void* d_out, int out_size, void* d_ws, size_t ws_size,
                              hipStream_t stream) {
    const int*   user_ids    = (const int*)  d_in[0];
    const int*   item_ids    = (const int*)  d_in[1];
    const float* item_know   = (const float*)d_in[2];
    const float* priori      = (const float*)d_in[3];
    const float* condi_p     = (const float*)d_in[4];
    const float* condi_n     = (const float*)d_in[5];
    const float* item_diff_w = (const float*)d_in[6];
    const float* item_disc_w = (const float*)d_in[7];
    const float* Wu          = (const float*)d_in[8];
    const float* bu          = (const float*)d_in[9];
    const float* Wi          = (const float*)d_in[10];
    const float* bi          = (const float*)d_in[11];
    float* out = (float*)d_out;

    char* base = (char*)d_ws;
    u16* wsp   = (u16*)base;                                   // 256 KiB
    u32* mhi32 = (u32*)(base + 0x0040000);                     // 4 MiB
    u32* mlo32 = (u32*)(base + 0x0440000);                     // 4 MiB
    u16* dhi   = (u16*)(base + 0x0840000);                     // 4 MiB
    u16* dlo   = (u16*)(base + 0x0C40000);                     // 4 MiB
    const size_t need = 0x1040000;                             // ~16.25 MiB

    if (ws_size >= need) {
        prep3<<<BATCH / 4, 256, 0, stream>>>(
            user_ids, item_ids, item_know, priori, condi_p, condi_n,
            item_diff_w, Wu, Wi, wsp, mhi32, mlo32, dhi, dlo);
        gemm_ncd<<<BATCH / 32, 256, 0, stream>>>(
            item_ids, item_disc_w, bu, bi, wsp,
            mhi32, mlo32, (const u32*)dhi, (const u32*)dlo, out);
    } else {
        conv_w<<<256, 256, 0, stream>>>(Wu, Wi, wsp);
        fused_ncd<<<BATCH / RPB, 256, 0, stream>>>(
            user_ids, item_ids, item_know, priori, condi_p, condi_n,
            item_diff_w, item_disc_w, bu, bi, wsp, out);
    }
}

// Round 12
// 58.419 us; speedup vs baseline: 1.5983x; 1.5983x over previous
//
#include <hip/hip_runtime.h>

#define BATCH   16384
#define NKNOW   128
#define NEDGE   253
#define NROW    16      // rows per block in mega kernel

typedef __attribute__((ext_vector_type(8))) short  s16x8;   // 8 bf16 MFMA operand
typedef __attribute__((ext_vector_type(4))) float  f32x4;   // MFMA accumulator
typedef __attribute__((ext_vector_type(4))) int    i32x4;

typedef unsigned short u16;
typedef unsigned int   u32;
typedef unsigned long long u64;

__device__ __forceinline__ float sigm(float x) { return 1.0f / (1.0f + __expf(-x)); }

__device__ __forceinline__ u16 f2bf_rn(float x) {
    u32 u = __float_as_uint(x);
    u += 0x7FFFu + ((u >> 16) & 1u);
    return (u16)(u >> 16);
}
__device__ __forceinline__ float bf2f(u16 h) { return __uint_as_float(((u32)h) << 16); }

// R1-proven LDS swizzle: row-major 256B rows, XOR bits 4-6 with row&7
__device__ __forceinline__ int swz(int row, int kbyte) {
    return row * 256 + (kbyte ^ ((row & 7) << 4));
}
__device__ __forceinline__ void store_pair(char* Mh, char* Ml, int r, int k0, float va, float vb) {
    int off = swz(r, k0 * 2);
    u16 ha = f2bf_rn(va); u16 la = f2bf_rn(va - bf2f(ha));
    u16 hb = f2bf_rn(vb); u16 lb = f2bf_rn(vb - bf2f(hb));
    *(u32*)(Mh + off) = (u32)ha | ((u32)hb << 16);
    *(u32*)(Ml + off) = (u32)la | ((u32)lb << 16);
}

// ---- K1: Wu/Wi fp32 [256][128] -> bf16 hi/lo blocks in d_ws (proven) ------
__global__ void conv_w(const float* __restrict__ Wu, const float* __restrict__ Wi,
                       u16* __restrict__ wsp) {
    int i = blockIdx.x * 256 + threadIdx.x;
    bool isU = i < 32768;
    int  j   = isU ? i : i - 32768;
    float w  = isU ? Wu[j] : Wi[j];
    u16 h = f2bf_rn(w);
    u16 l = f2bf_rn(w - bf2f(h));
    int base = isU ? 0 : 65536;
    wsp[base + j]         = h;
    wsp[base + 32768 + j] = l;
}

// ======================= K2: mega (gather+chain+D-prep+gemm) ===============
// 1024 blocks x 512 thr (8 waves), 16 rows/block. ~53 KB LDS -> 2 blocks/CU.
// Phase 1: wave w gathers rows 2w,2w+1 (ALL loads issued up front, R7-style),
//          sigmoid+sqrt -> sP; know/diff -> sDh/sDl/sKm (swizzled, R1-style).
// Phase 2: 16 chains on 16 lanes of wave 0 (R9-proven LDS pipeline,
//          R8-proven unmasked store_pair into swizzled sMh/sMl).
// Phase 3: waves 0-3 = R1-fused-proven MFMA gemm (km AND, bf16x3).
__global__ __launch_bounds__(512, 4) void mega_ncd(
    const int*   __restrict__ user_ids,
    const int*   __restrict__ item_ids,
    const float* __restrict__ item_know,
    const float* __restrict__ priori,
    const float* __restrict__ condi_p,
    const float* __restrict__ condi_n,
    const float* __restrict__ item_diff_w,
    const float* __restrict__ item_disc_w,
    const float* __restrict__ bu,
    const float* __restrict__ bi,
    const u16*   __restrict__ wsp,
    float*       __restrict__ out)
{
    __shared__ float4 sP[NROW][127];                 // 32.5 KB
    __shared__ __align__(16) u16 sMh[NROW * 128];    // 4 KB each
    __shared__ __align__(16) u16 sMl[NROW * 128];
    __shared__ __align__(16) u16 sDh[NROW * 128];
    __shared__ __align__(16) u16 sDl[NROW * 128];
    __shared__ __align__(16) u16 sKm[NROW * 128];
    __shared__ float sRed[4][NROW];
    __shared__ float sDisc[NROW];

    const int tid = threadIdx.x;
    const int wid = tid >> 6, j = tid & 63;
    const int r0  = blockIdx.x * NROW;

    if (tid < NROW) sDisc[tid] = sigm(item_disc_w[item_ids[r0 + tid]]);

    // ---------------- Phase 1: 2 rows per wave, loads up front ------------
    {
        const int rA = wid * 2, rB = rA + 1;
        const int rowA = r0 + rA, rowB = r0 + rB;
        const int uidA = user_ids[rowA], uidB = user_ids[rowB];
        const int iidA = item_ids[rowA], iidB = item_ids[rowB];
        const float* cpA = condi_p + (size_t)uidA * NEDGE;
        const float* cnA = condi_n + (size_t)uidA * NEDGE;
        const float* cpB = condi_p + (size_t)uidB * NEDGE;
        const float* cnB = condi_n + (size_t)uidB * NEDGE;
        const float* kwA = item_know   + (size_t)rowA * NKNOW;
        const float* kwB = item_know   + (size_t)rowB * NKNOW;
        const float* dwA = item_diff_w + (size_t)iidA * NKNOW;
        const float* dwB = item_diff_w + (size_t)iidB * NKNOW;

        // independent loads for BOTH rows issued before any use
        float Aa0p = cpA[127 + j], Aa0n = cnA[127 + j], Ab0p = cpA[1 + j], Ab0n = cnA[1 + j];
        float Ba0p = cpB[127 + j], Ba0n = cnB[127 + j], Bb0p = cpB[1 + j], Bb0n = cnB[1 + j];
        float Aa1p = 0.f, Aa1n = 0.f, Ab1p = 0.f, Ab1n = 0.f;
        float Ba1p = 0.f, Ba1n = 0.f, Bb1p = 0.f, Bb1n = 0.f;
        if (j < 62) {
            Aa1p = cpA[191 + j]; Aa1n = cnA[191 + j]; Ab1p = cpA[65 + j]; Ab1n = cnA[65 + j];
            Ba1p = cpB[191 + j]; Ba1n = cnB[191 + j]; Bb1p = cpB[65 + j]; Bb1n = cnB[65 + j];
        }
        float Ak0 = kwA[j], Ak1 = kwA[64 + j], Ad0 = dwA[j], Ad1 = dwA[64 + j];
        float Bk0 = kwB[j], Bk1 = kwB[64 + j], Bd0 = dwB[j], Bd1 = dwB[64 + j];
        float Ac0p = cpA[0], Ac0n = cnA[0], Apri = priori[(size_t)uidA * NKNOW];
        float Bc0p = cpB[0], Bc0n = cnB[0], Bpri = priori[(size_t)uidB * NKNOW];

        float4 q;
        q.x = sqrtf(sigm(Aa0p)); q.y = sqrtf(sigm(Aa0n));
        q.z = sqrtf(sigm(Ab0p)); q.w = sqrtf(sigm(Ab0n));
        sP[rA][1 + j] = q;
        q.x = sqrtf(sigm(Ba0p)); q.y = sqrtf(sigm(Ba0n));
        q.z = sqrtf(sigm(Bb0p)); q.w = sqrtf(sigm(Bb0n));
        sP[rB][1 + j] = q;
        if (j < 62) {
            q.x = sqrtf(sigm(Aa1p)); q.y = sqrtf(sigm(Aa1n));
            q.z = sqrtf(sigm(Ab1p)); q.w = sqrtf(sigm(Ab1n));
            sP[rA][65 + j] = q;
            q.x = sqrtf(sigm(Ba1p)); q.y = sqrtf(sigm(Ba1n));
            q.z = sqrtf(sigm(Bb1p)); q.w = sqrtf(sigm(Bb1n));
            sP[rB][65 + j] = q;
        }

        {   // D-prep row A (know in {0,1} -> exact)
            float dv0 = sigm(Ad0) * Ak0, dv1 = sigm(Ad1) * Ak1;
            u16 h0 = f2bf_rn(dv0), h1 = f2bf_rn(dv1);
            const int o0 = swz(rA, 2 * j), o1 = swz(rA, 2 * (64 + j));
            *(u16*)((char*)sDh + o0) = h0;
            *(u16*)((char*)sDl + o0) = f2bf_rn(dv0 - bf2f(h0));
            *(u16*)((char*)sKm + o0) = (Ak0 > 0.5f) ? (u16)0xFFFFu : (u16)0;
            *(u16*)((char*)sDh + o1) = h1;
            *(u16*)((char*)sDl + o1) = f2bf_rn(dv1 - bf2f(h1));
            *(u16*)((char*)sKm + o1) = (Ak1 > 0.5f) ? (u16)0xFFFFu : (u16)0;
        }
        {   // D-prep row B
            float dv0 = sigm(Bd0) * Bk0, dv1 = sigm(Bd1) * Bk1;
            u16 h0 = f2bf_rn(dv0), h1 = f2bf_rn(dv1);
            const int o0 = swz(rB, 2 * j), o1 = swz(rB, 2 * (64 + j));
            *(u16*)((char*)sDh + o0) = h0;
            *(u16*)((char*)sDl + o0) = f2bf_rn(dv0 - bf2f(h0));
            *(u16*)((char*)sKm + o0) = (Bk0 > 0.5f) ? (u16)0xFFFFu : (u16)0;
            *(u16*)((char*)sDh + o1) = h1;
            *(u16*)((char*)sDl + o1) = f2bf_rn(dv1 - bf2f(h1));
            *(u16*)((char*)sKm + o1) = (Bk1 > 0.5f) ? (u16)0xFFFFu : (u16)0;
        }
        if (j == 0) {
            float4 h;
            h.x = sigm(Ac0p); h.y = sigm(Ac0n); h.z = sigm(Apri); h.w = 0.f;
            sP[rA][0] = h;
            h.x = sigm(Bc0p); h.y = sigm(Bc0n); h.z = sigm(Bpri); h.w = 0.f;
            sP[rB][0] = h;
        }
    }
    __syncthreads();

    // ---------------- Phase 2: 16 chains on 16 lanes (wave 0) -------------
    if (tid < NROW) {
        const int r = tid;
        float4 h = sP[r][0];
        float p0 = h.z;
        float p1 = fmaf(p0, h.x - h.y, h.y);
        store_pair((char*)sMh, (char*)sMl, r, 0, p0, p1);

        float pm2 = p0, pm1 = p1, pev = 0.f;
        float4 A[7], Bv[7];

#define LOADB(buf, bi_)                                               \
    _Pragma("unroll")                                                 \
    for (int t = 0; t < 7; ++t) buf[t] = sP[r][1 + 7 * (bi_) + t];

#define STEPS(buf, bi_)                                               \
    _Pragma("unroll")                                                 \
    for (int t = 0; t < 7; ++t) {                                     \
        const int k = 2 + 7 * (bi_) + t;                              \
        float4 s = buf[t];                                            \
        float ta = fmaf(pm2, s.x - s.y, s.y);                         \
        float tb = fmaf(pm1, s.z - s.w, s.w);                         \
        float pk = ta * tb;                                           \
        if (k & 1) store_pair((char*)sMh, (char*)sMl, r, k - 1, pev, pk); \
        else       pev = pk;                                          \
        pm2 = pm1; pm1 = pk;                                          \
    }
        LOADB(A, 0);
        LOADB(Bv, 1);  STEPS(A, 0);
        LOADB(A, 2);   STEPS(Bv, 1);
        LOADB(Bv, 3);  STEPS(A, 2);
        LOADB(A, 4);   STEPS(Bv, 3);
        LOADB(Bv, 5);  STEPS(A, 4);
        LOADB(A, 6);   STEPS(Bv, 5);
        LOADB(Bv, 7);  STEPS(A, 6);
        LOADB(A, 8);   STEPS(Bv, 7);
        LOADB(Bv, 9);  STEPS(A, 8);
        LOADB(A, 10);  STEPS(Bv, 9);
        LOADB(Bv, 11); STEPS(A, 10);
        LOADB(A, 12);  STEPS(Bv, 11);
        LOADB(Bv, 13); STEPS(A, 12);
        LOADB(A, 14);  STEPS(Bv, 13);
        LOADB(Bv, 15); STEPS(A, 14);
        LOADB(A, 16);  STEPS(Bv, 15);
        LOADB(Bv, 17); STEPS(A, 16);
        STEPS(Bv, 17);
#undef LOADB
#undef STEPS
    }
    __syncthreads();

    // ---------------- Phase 3: MFMA gemm (waves 0-3, R1-fused-proven) -----
    if (wid < 4) {
        const int l15 = j & 15, lq = j >> 4;
        const u16* WuH = wsp;
        const u16* WuL = wsp + 32768;
        const u16* WiH = wsp + 65536;
        const u16* WiL = wsp + 98304;

        float rowsum[4] = {0.f, 0.f, 0.f, 0.f};

        #pragma unroll 1
        for (int t = 0; t < 4; ++t) {
            const int hcol = wid * 64 + t * 16 + l15;
            f32x4 accU = {0.f, 0.f, 0.f, 0.f};
            f32x4 accV = {0.f, 0.f, 0.f, 0.f};
            const u16* wuh = WuH + hcol * NKNOW;
            const u16* wul = WuL + hcol * NKNOW;
            const u16* wih = WiH + hcol * NKNOW;
            const u16* wil = WiL + hcol * NKNOW;
            #pragma unroll
            for (int kc = 0; kc < 4; ++kc) {
                const int offA = swz(l15, kc * 64 + lq * 16);
                const int ke   = kc * 32 + lq * 8;
                i32x4 km = *(const i32x4*)((const char*)sKm + offA);
                i32x4 mh = *(const i32x4*)((const char*)sMh + offA) & km;
                i32x4 ml = *(const i32x4*)((const char*)sMl + offA) & km;
                s16x8 ah = *(s16x8*)&mh;
                s16x8 al = *(s16x8*)&ml;
                s16x8 bh = *(const s16x8*)((const char*)sDh + offA);
                s16x8 bl = *(const s16x8*)((const char*)sDl + offA);
                s16x8 uh = *(const s16x8*)(wuh + ke);
                s16x8 ul = *(const s16x8*)(wul + ke);
                s16x8 ih = *(const s16x8*)(wih + ke);
                s16x8 il = *(const s16x8*)(wil + ke);
                accU = __builtin_amdgcn_mfma_f32_16x16x32_bf16(ah, uh, accU, 0, 0, 0);
                accU = __builtin_amdgcn_mfma_f32_16x16x32_bf16(ah, ul, accU, 0, 0, 0);
                accU = __builtin_amdgcn_mfma_f32_16x16x32_bf16(al, uh, accU, 0, 0, 0);
                accV = __builtin_amdgcn_mfma_f32_16x16x32_bf16(bh, ih, accV, 0, 0, 0);
                accV = __builtin_amdgcn_mfma_f32_16x16x32_bf16(bh, il, accV, 0, 0, 0);
                accV = __builtin_amdgcn_mfma_f32_16x16x32_bf16(bl, ih, accV, 0, 0, 0);
            }
            const float bub = bu[hcol], bib = bi[hcol];
            #pragma unroll
            for (int jj = 0; jj < 4; ++jj) {             // C/D: col=l15, row=lq*4+jj
                float x = accU[jj] + bub;
                float u = 1.0f - 2.0f / (1.0f + __expf(2.0f * x));   // tanh
                float v = sigm(accV[jj] + bib);
                rowsum[jj] += u * v;
            }
        }

        #pragma unroll
        for (int jj = 0; jj < 4; ++jj) {
            float v = rowsum[jj];
            v += __shfl_xor(v, 1);
            v += __shfl_xor(v, 2);
            v += __shfl_xor(v, 4);
            v += __shfl_xor(v, 8);
            if (l15 == 0) sRed[wid][lq * 4 + jj] = v;
        }
    }
    __syncthreads();

    if (tid < NROW) {
        float s = sRed[0][tid] + sRed[1][tid] + sRed[2][tid] + sRed[3][tid];
        out[r0 + tid] = sigm(s - sDisc[tid]);
    }
}

extern "C" void kernel_launch(void* const* d_in, const int* in_sizes, int n_in,
                              void* d_out, int out_size, void* d_ws, size_t ws_size,
                              hipStream_t stream) {
    const int*   user_ids    = (const int*)  d_in[0];
    const int*   item_ids    = (const int*)  d_in[1];
    const float* item_know   = (const float*)d_in[2];
    const float* priori      = (const float*)d_in[3];
    const float* condi_p     = (const float*)d_in[4];
    const float* condi_n     = (const float*)d_in[5];
    const float* item_diff_w = (const float*)d_in[6];
    const float* item_disc_w = (const float*)d_in[7];
    const float* Wu          = (const float*)d_in[8];
    const float* bu          = (const float*)d_in[9];
    const float* Wi          = (const float*)d_in[10];
    const float* bi          = (const float*)d_in[11];
    float* out = (float*)d_out;

    u16* wsp = (u16*)d_ws;                       // 256 KiB (ws observed ~810 MB)

    conv_w<<<256, 256, 0, stream>>>(Wu, Wi, wsp);
    mega_ncd<<<BATCH / NROW, 512, 0, stream>>>(
        user_ids, item_ids, item_know, priori, condi_p, condi_n,
        item_diff_w, item_disc_w, bu, bi, wsp, out);
}

// Round 14
// 53.069 us; speedup vs baseline: 1.7595x; 1.1008x over previous
//
#include <hip/hip_runtime.h>

#define BATCH   16384
#define NKNOW   128
#define NEDGE   253
#define RPB     16

typedef __attribute__((ext_vector_type(8))) short  s16x8;   // 8 bf16 MFMA operand
typedef __attribute__((ext_vector_type(4))) float  f32x4;   // MFMA accumulator
typedef __attribute__((ext_vector_type(4))) int    i32x4;

typedef unsigned short u16;
typedef unsigned int   u32;
typedef unsigned long long u64;

__device__ __forceinline__ float sigm(float x) { return 1.0f / (1.0f + __expf(-x)); }

__device__ __forceinline__ u16 f2bf_rn(float x) {
    u32 u = __float_as_uint(x);
    u += 0x7FFFu + ((u >> 16) & 1u);
    return (u16)(u >> 16);
}
__device__ __forceinline__ float bf2f(u16 h) { return __uint_as_float(((u32)h) << 16); }

// R1-proven LDS swizzle: row-major 256B rows, XOR bits 4-6 with row&7
__device__ __forceinline__ int swz(int row, int kbyte) {
    return row * 256 + (kbyte ^ ((row & 7) << 4));
}
__device__ __forceinline__ void store_pair(char* Mh, char* Ml, int r, int k0, float va, float vb) {
    int off = swz(r, k0 * 2);
    u16 ha = f2bf_rn(va); u16 la = f2bf_rn(va - bf2f(ha));
    u16 hb = f2bf_rn(vb); u16 lb = f2bf_rn(vb - bf2f(hb));
    *(u32*)(Mh + off) = (u32)ha | ((u32)hb << 16);
    *(u32*)(Ml + off) = (u32)la | ((u32)lb << 16);
}

// ======================= K1: gather (+ merged conv_w) — champion verbatim ==
// cbT[slot][row] (slot-major, BATCH stride):
//   slot 0      = header (sig cp0, sig cn0, sig priori0, 0)
//   slot 1..126 = step k=slot+1: (cpa,cna,cpb,cnb) sqrt'd sigmoids
__global__ __launch_bounds__(256, 4) void gather_ncd(
    const int*   __restrict__ user_ids,
    const float* __restrict__ priori,
    const float* __restrict__ condi_p,
    const float* __restrict__ condi_n,
    const float* __restrict__ Wu,
    const float* __restrict__ Wi,
    u16*         __restrict__ wsp,
    float4*      __restrict__ cbT)
{
    __shared__ float4 stage[4][128];        // [rr][slot], 8 KB

    const int wid = threadIdx.x >> 6, j = threadIdx.x & 63;
    const int r0  = blockIdx.x * 4;
    const int row = r0 + wid;
    const int uid = user_ids[row];
    const float* cp = condi_p + (size_t)uid * NEDGE;
    const float* cn = condi_n + (size_t)uid * NEDGE;

    // issue all independent loads up front
    float a0p = cp[127 + j], a0n = cn[127 + j], b0p = cp[1 + j], b0n = cn[1 + j];
    float a1p = 0.f, a1n = 0.f, b1p = 0.f, b1n = 0.f;
    if (j < 62) { a1p = cp[191 + j]; a1n = cn[191 + j]; b1p = cp[65 + j]; b1n = cn[65 + j]; }
    float c0p = cp[0], c0n = cn[0], pri = priori[(size_t)uid * NKNOW];

    float4 sA;
    sA.x = sqrtf(sigm(a0p)); sA.y = sqrtf(sigm(a0n));
    sA.z = sqrtf(sigm(b0p)); sA.w = sqrtf(sigm(b0n));
    stage[wid][1 + j] = sA;
    if (j < 62) {
        float4 sB;
        sB.x = sqrtf(sigm(a1p)); sB.y = sqrtf(sigm(a1n));
        sB.z = sqrtf(sigm(b1p)); sB.w = sqrtf(sigm(b1n));
        stage[wid][65 + j] = sB;
    }
    if (j == 0) {
        float4 h; h.x = sigm(c0p); h.y = sigm(c0n); h.z = sigm(pri); h.w = 0.f;
        stage[wid][0] = h;
    }
    __syncthreads();

    // transposed write-out: 127 slots x 4 rows, 64B-contiguous per slot
    for (int idx = threadIdx.x; idx < 4 * 127; idx += 256) {
        const int slot = idx >> 2, rr = idx & 3;
        cbT[(size_t)slot * BATCH + r0 + rr] = stage[rr][slot];
    }

    // merged conv_w: blocks 0..255 convert Wu/Wi fp32 -> bf16 hi/lo in wsp
    if (blockIdx.x < 256) {
        int i = blockIdx.x * 256 + threadIdx.x;          // 0..65535
        bool isU = i < 32768;
        int  jj  = isU ? i : i - 32768;
        float w  = isU ? Wu[jj] : Wi[jj];
        u16 h = f2bf_rn(w);
        u16 l = f2bf_rn(w - bf2f(h));
        int base = isU ? 0 : 65536;
        wsp[base + jj]         = h;
        wsp[base + 32768 + jj] = l;
    }
}

// ======================= K2: chain ∥ D-prep + gemm (v2) ====================
// 512 blocks x 256 thr, 32 rows/block, ~40 KB LDS -> 3 blocks/CU.
// CONCURRENT phase A (no internal barrier):
//   wave0 lanes 0-31 : 32 serial chains (coalesced cbT reads, champion code)
//   wave0 lanes 32-63: disc
//   waves 1-3        : flat element-parallel D-prep (4096 elems / 192 thr,
//                      all loads independent -> full MLP)
// Then one barrier; phase B = champion MFMA gemm (km AND, bf16x3).
__global__ __launch_bounds__(256, 2) void cg_ncd(
    const int*   __restrict__ item_ids,
    const float* __restrict__ item_know,
    const float* __restrict__ item_diff_w,
    const float* __restrict__ item_disc_w,
    const float* __restrict__ bu,
    const float* __restrict__ bi,
    const u16*   __restrict__ wsp,
    const float4* __restrict__ cbT,
    float*       __restrict__ out)
{
    __shared__ __align__(16) u16 sMh[32 * 128];
    __shared__ __align__(16) u16 sMl[32 * 128];
    __shared__ __align__(16) u16 sDh[32 * 128];
    __shared__ __align__(16) u16 sDl[32 * 128];
    __shared__ __align__(16) u16 sKm[32 * 128];
    __shared__ float sRed[4][32];
    __shared__ float sDisc[32];

    const int tid  = threadIdx.x;
    const int lane = tid & 63;
    const int wid  = tid >> 6;
    const int l15  = lane & 15, lq = lane >> 4;
    const int r0   = blockIdx.x * 32;

    if (wid == 0) {
        if (lane < 32) {
            // ---- 32 serial chains, coalesced cbT reads (champion verbatim)
            const int r = lane;
            const float4* base = cbT + (r0 + r);
            float4 h = base[0];
            float p0 = h.z;
            float p1 = fmaf(p0, h.x - h.y, h.y);
            store_pair((char*)sMh, (char*)sMl, r, 0, p0, p1);

            float pm2 = p0, pm1 = p1, pev = 0.f;
            float4 A[14], Bv[14];
#define LOADB(buf, bi_)                                               \
    _Pragma("unroll")                                                 \
    for (int t = 0; t < 14; ++t)                                      \
        buf[t] = base[(size_t)(1 + 14 * (bi_) + t) * BATCH];
#define STEPS(buf, bi_)                                               \
    _Pragma("unroll")                                                 \
    for (int t = 0; t < 14; ++t) {                                    \
        const int k = 2 + 14 * (bi_) + t;                             \
        float4 s = buf[t];                                            \
        float ta = fmaf(pm2, s.x - s.y, s.y);                         \
        float tb = fmaf(pm1, s.z - s.w, s.w);                         \
        float pk = ta * tb;                                           \
        if (k & 1) store_pair((char*)sMh, (char*)sMl, r, k - 1, pev, pk); \
        else       pev = pk;                                          \
        pm2 = pm1; pm1 = pk;                                          \
    }
            LOADB(A, 0);
            LOADB(Bv, 1); STEPS(A, 0);
            LOADB(A, 2);  STEPS(Bv, 1);
            LOADB(Bv, 3); STEPS(A, 2);
            LOADB(A, 4);  STEPS(Bv, 3);
            LOADB(Bv, 5); STEPS(A, 4);
            LOADB(A, 6);  STEPS(Bv, 5);
            LOADB(Bv, 7); STEPS(A, 6);
            LOADB(A, 8);  STEPS(Bv, 7);
            STEPS(A, 8);
#undef LOADB
#undef STEPS
        } else {
            sDisc[lane - 32] = sigm(item_disc_w[item_ids[r0 + lane - 32]]);
        }
    } else {
        // ---- waves 1-3: flat D-prep, 4096 elements / 192 threads ---------
        const int t192 = tid - 64;                       // 0..191
        for (int e = t192; e < 32 * NKNOW; e += 192) {
            const int r = e >> 7, c = e & 127;
            const int row = r0 + r;
            const int iid = item_ids[row];               // L1-cached, independent
            float kv = item_know[(size_t)row * NKNOW + c];
            float dv = sigm(item_diff_w[(size_t)iid * NKNOW + c]) * kv;  // exact
            u16 dh = f2bf_rn(dv);
            const int off = swz(r, 2 * c);
            *(u16*)((char*)sDh + off) = dh;
            *(u16*)((char*)sDl + off) = f2bf_rn(dv - bf2f(dh));
            *(u16*)((char*)sKm + off) = (kv > 0.5f) ? (u16)0xFFFFu : (u16)0;
        }
    }
    __syncthreads();

    // ---------------- Phase B: MFMA gemm (champion verbatim) --------------
    const u16* WuH = wsp;
    const u16* WuL = wsp + 32768;
    const u16* WiH = wsp + 65536;
    const u16* WiL = wsp + 98304;

    float rowsum[2][4] = {{0.f,0.f,0.f,0.f},{0.f,0.f,0.f,0.f}};

    #pragma unroll 1
    for (int t = 0; t < 4; ++t) {
        const int hcol = wid * 64 + t * 16 + l15;
        s16x8 uh[4], ul[4], ih[4], il[4];
        #pragma unroll
        for (int kc = 0; kc < 4; ++kc) {
            const int ke = kc * 32 + lq * 8;
            uh[kc] = *(const s16x8*)(WuH + hcol * NKNOW + ke);
            ul[kc] = *(const s16x8*)(WuL + hcol * NKNOW + ke);
            ih[kc] = *(const s16x8*)(WiH + hcol * NKNOW + ke);
            il[kc] = *(const s16x8*)(WiL + hcol * NKNOW + ke);
        }
        const float bub = bu[hcol], bib = bi[hcol];

        #pragma unroll
        for (int rg = 0; rg < 2; ++rg) {
            const int lr = rg * 16 + l15;                 // LDS row 0..31
            f32x4 accU = {0.f, 0.f, 0.f, 0.f};
            f32x4 accV = {0.f, 0.f, 0.f, 0.f};
            #pragma unroll
            for (int kc = 0; kc < 4; ++kc) {
                const int offA = swz(lr, kc * 64 + lq * 16);
                i32x4 km = *(const i32x4*)((const char*)sKm + offA);
                i32x4 mh = *(const i32x4*)((const char*)sMh + offA) & km;
                i32x4 ml = *(const i32x4*)((const char*)sMl + offA) & km;
                s16x8 ah = *(s16x8*)&mh;
                s16x8 al = *(s16x8*)&ml;
                s16x8 dh = *(const s16x8*)((const char*)sDh + offA);
                s16x8 dl = *(const s16x8*)((const char*)sDl + offA);
                accU = __builtin_amdgcn_mfma_f32_16x16x32_bf16(ah, uh[kc], accU, 0, 0, 0);
                accU = __builtin_amdgcn_mfma_f32_16x16x32_bf16(ah, ul[kc], accU, 0, 0, 0);
                accU = __builtin_amdgcn_mfma_f32_16x16x32_bf16(al, uh[kc], accU, 0, 0, 0);
                accV = __builtin_amdgcn_mfma_f32_16x16x32_bf16(dh, ih[kc], accV, 0, 0, 0);
                accV = __builtin_amdgcn_mfma_f32_16x16x32_bf16(dh, il[kc], accV, 0, 0, 0);
                accV = __builtin_amdgcn_mfma_f32_16x16x32_bf16(dl, ih[kc], accV, 0, 0, 0);
            }
            #pragma unroll
            for (int j = 0; j < 4; ++j) {                 // C/D: col=l15, row=lq*4+j
                float x = accU[j] + bub;
                float u = 1.0f - 2.0f / (1.0f + __expf(2.0f * x));   // tanh
                float v = sigm(accV[j] + bib);
                rowsum[rg][j] += u * v;
            }
        }
    }

    #pragma unroll
    for (int rg = 0; rg < 2; ++rg)
        #pragma unroll
        for (int j = 0; j < 4; ++j) {
            float v = rowsum[rg][j];
            v += __shfl_xor(v, 1);
            v += __shfl_xor(v, 2);
            v += __shfl_xor(v, 4);
            v += __shfl_xor(v, 8);
            if (l15 == 0) sRed[wid][rg * 16 + lq * 4 + j] = v;
        }
    __syncthreads();

    if (tid < 32) {
        float s = sRed[0][tid] + sRed[1][tid] + sRed[2][tid] + sRed[3][tid];
        out[r0 + tid] = sigm(s - sDisc[tid]);
    }
}

// ======================= Fallback: R1 fused kernel (proven) ================
__global__ void conv_w(const float* __restrict__ Wu, const float* __restrict__ Wi,
                       u16* __restrict__ wsp) {
    int i = blockIdx.x * 256 + threadIdx.x;
    bool isU = i < 32768;
    int  j   = isU ? i : i - 32768;
    float w  = isU ? Wu[j] : Wi[j];
    u16 h = f2bf_rn(w);
    u16 l = f2bf_rn(w - bf2f(h));
    int base = isU ? 0 : 65536;
    wsp[base + j]         = h;
    wsp[base + 32768 + j] = l;
}

__global__ __launch_bounds__(256, 3) void fused_ncd(
    const int*   __restrict__ user_ids,
    const int*   __restrict__ item_ids,
    const float* __restrict__ item_know,
    const float* __restrict__ priori,
    const float* __restrict__ condi_p,
    const float* __restrict__ condi_n,
    const float* __restrict__ item_diff_w,
    const float* __restrict__ item_disc_w,
    const float* __restrict__ bu,
    const float* __restrict__ bi,
    const u16* __restrict__ wsp,
    float*       __restrict__ out)
{
    __shared__ float sPair[RPB][508];
    __shared__ __align__(16) u16 sMhi[RPB * 128];
    __shared__ __align__(16) u16 sMlo[RPB * 128];
    __shared__ __align__(16) u16 sDhi[RPB * 128];
    __shared__ __align__(16) u16 sDlo[RPB * 128];
    __shared__ __align__(16) u16 sKmF[RPB * 128];
    __shared__ float sRed[4][RPB];
    __shared__ float sDisc[RPB];

    const int tid  = threadIdx.x;
    const int lane = tid & 63;
    const int wid  = tid >> 6;
    const int r0   = blockIdx.x * RPB;

    for (int rr = 0; rr < 4; ++rr) {
        const int r   = wid * 4 + rr;
        const int row = r0 + r;
        const int uid = user_ids[row];
        const int iid = item_ids[row];
        const float* cp = condi_p + (size_t)uid * NEDGE;
        const float* cn = condi_n + (size_t)uid * NEDGE;
        for (int e = lane; e < NEDGE; e += 64) {
            float p = sigm(cp[e]);
            float n = sigm(cn[e]);
            if (e >= 1) { p = sqrtf(p); n = sqrtf(n); }
            *(float2*)&sPair[r][2 * e] = make_float2(p, n);
        }
        const float* dw = item_diff_w + (size_t)iid * NKNOW;
        const float* kw = item_know   + (size_t)row * NKNOW;
        for (int e = lane; e < NKNOW; e += 64) {
            float kv = kw[e];
            float dv = sigm(dw[e]) * kv;
            u16 dh = f2bf_rn(dv);
            u16 dl = f2bf_rn(dv - bf2f(dh));
            int off = swz(r, 2 * e);
            *(u16*)((char*)sDhi + off) = dh;
            *(u16*)((char*)sDlo + off) = dl;
            *(u16*)((char*)sKmF + off) = (kv > 0.5f) ? (u16)0xFFFFu : (u16)0;
        }
    }
    __syncthreads();

    if (tid < RPB) {
        const int r   = tid;
        const int row = r0 + r;
        const int uid = user_ids[row];
        const int iid = item_ids[row];
        const float* P = &sPair[r][0];
        float p0 = sigm(priori[(size_t)uid * NKNOW]);
        float2 c0 = *(const float2*)&P[0];
        float p1 = c0.x * p0 + c0.y * (1.0f - p0);
        store_pair((char*)sMhi, (char*)sMlo, r, 0, p0, p1);
        float pm2 = p0, pm1 = p1, pev = 0.0f;
        for (int k = 2; k < NKNOW; ++k) {
            float2 a = *(const float2*)&P[2 * (125 + k)];
            float2 b = *(const float2*)&P[2 * (k - 1)];
            float ta = fmaf(pm2, a.x - a.y, a.y);
            float tb = fmaf(pm1, b.x - b.y, b.y);
            float pk = ta * tb;
            if (k & 1) store_pair((char*)sMhi, (char*)sMlo, r, k - 1, pev, pk);
            else       pev = pk;
            pm2 = pm1; pm1 = pk;
        }
        sDisc[r] = sigm(item_disc_w[iid]);
    }
    __syncthreads();

    const int l15 = lane & 15, lq = lane >> 4;
    const u16* WuH = wsp;
    const u16* WuL = wsp + 32768;
    const u16* WiH = wsp + 65536;
    const u16* WiL = wsp + 98304;

    float rowsum[4] = {0.f, 0.f, 0.f, 0.f};

    for (int t = 0; t < 4; ++t) {
        const int hcol = wid * 64 + t * 16 + l15;
        f32x4 accU = {0.f, 0.f, 0.f, 0.f};
        f32x4 accV = {0.f, 0.f, 0.f, 0.f};
        const u16* wuh = WuH + hcol * NKNOW;
        const u16* wul = WuL + hcol * NKNOW;
        const u16* wih = WiH + hcol * NKNOW;
        const u16* wil = WiL + hcol * NKNOW;
        #pragma unroll
        for (int kc = 0; kc < 4; ++kc) {
            const int offA = swz(l15, kc * 64 + lq * 16);
            const int ke   = kc * 32 + lq * 8;
            i32x4 km = *(const i32x4*)((const char*)sKmF + offA);
            i32x4 mh = *(const i32x4*)((const char*)sMhi + offA) & km;
            i32x4 ml = *(const i32x4*)((const char*)sMlo + offA) & km;
            s16x8 ah = *(s16x8*)&mh;
            s16x8 al = *(s16x8*)&ml;
            s16x8 bh = *(const s16x8*)((const char*)sDhi + offA);
            s16x8 bl = *(const s16x8*)((const char*)sDlo + offA);
            s16x8 uh = *(const s16x8*)(wuh + ke);
            s16x8 ul = *(const s16x8*)(wul + ke);
            s16x8 ih = *(const s16x8*)(wih + ke);
            s16x8 il = *(const s16x8*)(wil + ke);
            accU = __builtin_amdgcn_mfma_f32_16x16x32_bf16(ah, uh, accU, 0, 0, 0);
            accU = __builtin_amdgcn_mfma_f32_16x16x32_bf16(ah, ul, accU, 0, 0, 0);
            accU = __builtin_amdgcn_mfma_f32_16x16x32_bf16(al, uh, accU, 0, 0, 0);
            accV = __builtin_amdgcn_mfma_f32_16x16x32_bf16(bh, ih, accV, 0, 0, 0);
            accV = __builtin_amdgcn_mfma_f32_16x16x32_bf16(bh, il, accV, 0, 0, 0);
            accV = __builtin_amdgcn_mfma_f32_16x16x32_bf16(bl, ih, accV, 0, 0, 0);
        }
        const float bub = bu[hcol], bib = bi[hcol];
        #pragma unroll
        for (int j = 0; j < 4; ++j) {
            float x = accU[j] + bub;
            float u = 1.0f - 2.0f / (1.0f + __expf(2.0f * x));
            float v = sigm(accV[j] + bib);
            rowsum[j] += u * v;
        }
    }

    #pragma unroll
    for (int j = 0; j < 4; ++j) {
        float v = rowsum[j];
        v += __shfl_xor(v, 1);
        v += __shfl_xor(v, 2);
        v += __shfl_xor(v, 4);
        v += __shfl_xor(v, 8);
        if (l15 == 0) sRed[wid][lq * 4 + j] = v;
    }
    __syncthreads();

    if (tid < RPB) {
        float logit = sRed[0][tid] + sRed[1][tid] + sRed[2][tid] + sRed[3][tid] - sDisc[tid];
        out[r0 + tid] = sigm(logit);
    }
}

extern "C" void kernel_launch(void* const* d_in, const int* in_sizes, int n_in,
                              void* d_out, int out_size, void* d_ws, size_t ws_size,
                              hipStream_t stream) {
    const int*   user_ids    = (const int*)  d_in[0];
    const int*   item_ids    = (const int*)  d_in[1];
    const float* item_know   = (const float*)d_in[2];
    const float* priori      = (const float*)d_in[3];
    const float* condi_p     = (const float*)d_in[4];
    const float* condi_n     = (const float*)d_in[5];
    const float* item_diff_w = (const float*)d_in[6];
    const float* item_disc_w = (const float*)d_in[7];
    const float* Wu          = (const float*)d_in[8];
    const float* bu          = (const float*)d_in[9];
    const float* Wi          = (const float*)d_in[10];
    const float* bi          = (const float*)d_in[11];
    float* out = (float*)d_out;

    char* base = (char*)d_ws;
    u16*    wsp = (u16*)base;                                     // 256 KiB
    float4* cbT = (float4*)(base + 0x40000);                      // 127*BATCH*16 B
    const size_t need = 0x40000 + (size_t)127 * BATCH * 16;       // ~33.6 MiB

    if (ws_size >= need) {
        gather_ncd<<<BATCH / 4, 256, 0, stream>>>(
            user_ids, priori, condi_p, condi_n, Wu, Wi, wsp, cbT);
        cg_ncd<<<BATCH / 32, 256, 0, stream>>>(
            item_ids, item_know, item_diff_w, item_disc_w, bu, bi,
            wsp, cbT, out);
    } else {
        conv_w<<<256, 256, 0, stream>>>(Wu, Wi, wsp);
        fused_ncd<<<BATCH / RPB, 256, 0, stream>>>(
            user_ids, item_ids, item_know, priori, condi_p, condi_n,
            item_diff_w, item_disc_w, bu, bi, wsp, out);
    }
}